// Round 10
// baseline (689.505 us; speedup 1.0000x reference)
//
#include <hip/hip_runtime.h>
#include <math.h>

// ---------------------------------------------------------------------------
// TannerGNN. Round 10: k_msg rebuilt with 64x64 wave tiles (TE=256, 8 waves)
// to cut the LDS weight-broadcast traffic 4x per edge (it was LDS-BW-bound:
// ~171K cy/CU of LDS traffic vs 214K total). 1-chunk-lookahead weight
// staging register (VGPR<=128 for 2 blocks/CU), sMsg aliases sHid via 2-pass
// feat-split epilogue, XCD swizzle for dst/agg locality. Bit-identical
// K-order and reduction strips => absmax must stay exactly 0.02734375.
// k_gru/scan/readout unchanged from R9.
// N_NODES=50000, N_EDGES=400000, H=128, L=3, T=2, FEAT=4, N_DATA=40000.
// ---------------------------------------------------------------------------

#define H 128
#define TE3 256        // edges per message block (8 waves, 64x64 tiles)
#define HS3 136        // sHid row stride bf16 (272 B, 16B-aligned)
#define MS3 68         // sMsg row stride f32 (272 B), 64 feats + 4 pad
#define HS  136        // k_gru sIn stride
#define FEAT 4
#define WG_PER_LAYER 196608   // 2 mat * 2 split * 4 kc * 24 jtg * 64 lane * 8

typedef __bf16 bf16x8 __attribute__((ext_vector_type(8)));
typedef __bf16 bf16x4 __attribute__((ext_vector_type(4)));
typedef float  f32x4  __attribute__((ext_vector_type(4)));

// ---------------- input projection: h = relu(x @ W_in + b_in) --------------
__global__ __launch_bounds__(256) void k_input(
    const float* __restrict__ x, const float* __restrict__ Win,
    const float* __restrict__ bin, float* __restrict__ h,
    __bf16* __restrict__ hb, int n_nodes)
{
    int idx = blockIdx.x * 256 + threadIdx.x;
    if (idx >= n_nodes * H) return;
    int n = idx >> 7, j = idx & 127;
    float acc = bin[j];
#pragma unroll
    for (int f = 0; f < FEAT; f++)
        acc += x[n * FEAT + f] * Win[f * H + j];
    float v = fmaxf(acc, 0.f);
    h[idx] = v;
    hb[idx] = (__bf16)v;
}

// ---------------- message-weight conversion: bf16, MFMA-fragment order -----
__global__ __launch_bounds__(256) void k_wconv(
    const float* __restrict__ W1, const float* __restrict__ W2,
    __bf16* __restrict__ Wsw)
{
    int gid = blockIdx.x * 256 + threadIdx.x;
    const int per_lt = 12 * 4096;
    if (gid >= 6 * per_lt) return;
    int lt = gid / per_lt, rem = gid % per_lt;
    int chunk = rem >> 12;
    int within = rem & 4095;
    int ct = within >> 9;
    int lane = (within >> 3) & 63;
    int j = within & 7;
    int r = lane & 15, quad = lane >> 4;
    int n = ct * 16 + r;
    float v;
    if (chunk < 8) {
        int k = chunk * 32 + quad * 8 + j;
        v = W1[((size_t)lt * 256 + k) * 128 + n];
    } else {
        int k = (chunk - 8) * 32 + quad * 8 + j;
        v = W2[((size_t)lt * 128 + k) * 128 + n];
    }
    Wsw[gid] = (__bf16)v;
}

// ---------------- GRU-weight conversion: hi/lo split, B-fragment order -----
__global__ __launch_bounds__(256) void k_wgconv(
    const float* __restrict__ Wih, const float* __restrict__ Whh,
    __bf16* __restrict__ Wg)
{
    int gid = blockIdx.x * 256 + threadIdx.x;
    if (gid >= 3 * WG_PER_LAYER) return;
    int layer = gid / WG_PER_LAYER, rem = gid % WG_PER_LAYER;
    int t = rem & 7;
    int lane = (rem >> 3) & 63;
    int jtg = (rem >> 9) % 24;
    int mk = rem / 12288;          // (mat*2+split)*4 + kc, 0..15
    int kc = mk & 3;
    int msplit = mk >> 2;          // 0..3
    int mat = msplit >> 1, split = msplit & 1;
    int r = lane & 15, quad = lane >> 4;
    int k = kc * 32 + quad * 8 + t;
    int n = jtg * 16 + r;
    const float* W = (mat ? Whh : Wih) + (size_t)layer * 128 * 384;
    float v = W[(size_t)k * 384 + n];
    __bf16 hi = (__bf16)v;
    Wg[gid] = split ? (__bf16)(v - (float)hi) : hi;
}

// ---------------- counting sort by key = type*nn + dst ---------------------
__global__ __launch_bounds__(256) void k_hist(
    const int* __restrict__ et, const int* __restrict__ dst,
    int* __restrict__ cnt, int n_edges, int nn)
{
    int i = blockIdx.x * 256 + threadIdx.x;
    if (i < n_edges) atomicAdd(&cnt[et[i] * nn + dst[i]], 1);
}

__global__ __launch_bounds__(1024) void k_scan1(
    const int* __restrict__ cnt, int* __restrict__ bsum, int n)
{
    int i = blockIdx.x * 1024 + threadIdx.x;
    int v = (i < n) ? cnt[i] : 0;
#pragma unroll
    for (int off = 32; off > 0; off >>= 1) v += __shfl_down(v, off, 64);
    __shared__ int ws[16];
    int lane = threadIdx.x & 63, w = threadIdx.x >> 6;
    if (lane == 0) ws[w] = v;
    __syncthreads();
    if (threadIdx.x < 16) {
        int x = ws[threadIdx.x];
#pragma unroll
        for (int off = 8; off > 0; off >>= 1) x += __shfl_down(x, off, 64);
        if (threadIdx.x == 0) bsum[blockIdx.x] = x;
    }
}

__global__ __launch_bounds__(128) void k_scan2(
    int* __restrict__ bsum, int* __restrict__ offs, int nb, int n)
{
    int lane = threadIdx.x & 63, w = threadIdx.x >> 6;
    int v = (threadIdx.x < nb) ? bsum[threadIdx.x] : 0;
    int orig = v;
#pragma unroll
    for (int off = 1; off < 64; off <<= 1) {
        int t = __shfl_up(v, off, 64);
        if (lane >= off) v += t;
    }
    __shared__ int w0sum;
    if (threadIdx.x == 63) w0sum = v;
    __syncthreads();
    int ex = v - orig + (w ? w0sum : 0);
    if (threadIdx.x < nb) bsum[threadIdx.x] = ex;
    if (threadIdx.x == nb - 1) offs[n] = ex + orig;
}

__global__ __launch_bounds__(1024) void k_scan3(
    const int* __restrict__ cnt, const int* __restrict__ bsum,
    int* __restrict__ offs, int n)
{
    int i = blockIdx.x * 1024 + threadIdx.x;
    int v = (i < n) ? cnt[i] : 0;
    int orig = v;
    int lane = threadIdx.x & 63, w = threadIdx.x >> 6;
#pragma unroll
    for (int off = 1; off < 64; off <<= 1) {
        int t = __shfl_up(v, off, 64);
        if (lane >= off) v += t;
    }
    __shared__ int ws[16];
    if (lane == 63) ws[w] = v;
    __syncthreads();
    if (threadIdx.x < 16) {
        int x = ws[threadIdx.x];
#pragma unroll
        for (int off = 1; off < 16; off <<= 1) {
            int t = __shfl_up(x, off, 64);
            if (lane >= off) x += t;
        }
        ws[threadIdx.x] = x;
    }
    __syncthreads();
    int wbase = w ? ws[w - 1] : 0;
    if (i < n) offs[i] = bsum[blockIdx.x] + wbase + v - orig;
}

__global__ __launch_bounds__(256) void k_place(
    const int* __restrict__ et, const int* __restrict__ dst,
    const int* __restrict__ offs, int* __restrict__ cnt,
    int* __restrict__ bucket, int n_edges, int nn)
{
    int i = blockIdx.x * 256 + threadIdx.x;
    if (i < n_edges) {
        int key = et[i] * nn + dst[i];
        int p = atomicAdd(&cnt[key], -1) - 1;
        bucket[offs[key] + p] = i;
    }
}

// ---------------- fused MFMA message kernel: 64x64 wave tiles --------------
// Block = 256 dst-sorted edges of one type, 8 waves. Wave w: feat half
// f=w&1 (ct tiles 4f..4f+3), edge quarter q=w>>1 (subtiles et=0..3 of 16).
// Weight chunks streamed through one 8KB sW with a 1-lookahead register.
// Transposed MFMA (A=weight, B=edge), bit-identical K-order to R9.
__global__ __launch_bounds__(512, 4) void k_msg(
    const __bf16* __restrict__ hb,
    const int* __restrict__ bucket, const int* __restrict__ offs,
    const int* __restrict__ src, const int* __restrict__ dst,
    const __bf16* __restrict__ Wsw, const float* __restrict__ b1l,
    const float* __restrict__ b2l,
    float* __restrict__ agg, int n_edges, int nn)
{
    const int t = blockIdx.y;
    const int c0 = offs[nn];
    const int cnt = t ? (n_edges - c0) : c0;
    const int base = t ? c0 : 0;

    // XCD swizzle: contiguous chunk ranges per XCD (round-robin dispatch)
    const int B = (cnt + TE3 - 1) / TE3;
    const int cpx = (B + 7) >> 3;
    int bx = blockIdx.x;
    if (bx >= 8 * cpx) return;
    int chunk = (bx & 7) * cpx + (bx >> 3);
    if (chunk >= B) return;
    const int start = chunk * TE3;

    const __bf16* __restrict__ W = Wsw + (size_t)t * 12 * 4096;
    const float*  __restrict__ b1 = b1l + t * H;
    const float*  __restrict__ b2 = b2l + t * H;

    __shared__ __bf16 sW[4096];                 // 8 KB weight chunk
    __shared__ __bf16 sHid[TE3 * HS3];          // 69632 B; sMsg aliases
    float* sMsg = (float*)sHid;                 // stride MS3, 64 feats/pass
    __shared__ int sSrcN[TE3], sDstN[TE3], sDstV[TE3];

    const int tid  = threadIdx.x;
    const int lane = tid & 63;
    const int w    = tid >> 6;
    const int r    = lane & 15;
    const int quad = lane >> 4;
    const int f    = w & 1;
    const int q    = w >> 1;

    // lookahead register for weight chunk staging
    f32x4 wnext = *(const f32x4*)(W + tid * 8);     // chunk 0 slice

    if (tid < TE3) {
        int i = start + tid;
        int e = bucket[base + (i < cnt ? i : cnt - 1)];
        sSrcN[tid] = src[e];
        int d = dst[e];
        sDstN[tid] = d;
        sDstV[tid] = (i < cnt) ? d : -1;
    }
    __syncthreads();

    // per-lane edge pointers (src halves first)
    const __bf16* ep[4];
#pragma unroll
    for (int et = 0; et < 4; et++)
        ep[et] = hb + (size_t)sSrcN[q * 64 + et * 16 + r] * H;

    // ---- Phase A: hidT = (cat @ W1)^T, K=256 in 8 chunks ----
    f32x4 acc[4][4];                            // [c][et]
#pragma unroll
    for (int c = 0; c < 4; c++)
#pragma unroll
        for (int et = 0; et < 4; et++) acc[c][et] = (f32x4){0.f, 0.f, 0.f, 0.f};

#pragma unroll
    for (int kc = 0; kc < 8; kc++) {
        __syncthreads();                        // prev chunk consumed
        *(f32x4*)(sW + tid * 8) = wnext;
        wnext = *(const f32x4*)(W + (kc + 1) * 4096 + tid * 8);  // chunks 1..8
        __syncthreads();
        if (kc == 4) {                          // switch to dst halves
#pragma unroll
            for (int et = 0; et < 4; et++)
                ep[et] = hb + (size_t)sDstN[q * 64 + et * 16 + r] * H;
        }
        const int kk = (kc & 3) * 32 + quad * 8;
        bf16x8 Bf[4];
#pragma unroll
        for (int et = 0; et < 4; et++)
            Bf[et] = *(const bf16x8*)(ep[et] + kk);
        bf16x8 Af[4];
#pragma unroll
        for (int c = 0; c < 4; c++)
            Af[c] = *(const bf16x8*)(sW + (4 * f + c) * 512 + lane * 8);
#pragma unroll
        for (int c = 0; c < 4; c++)
#pragma unroll
            for (int et = 0; et < 4; et++)
                acc[c][et] = __builtin_amdgcn_mfma_f32_16x16x32_bf16(
                    Af[c], Bf[et], acc[c][et], 0, 0, 0);
    }

    // epilogue A: bias + relu -> bf16 -> sHid[edge][feat]
#pragma unroll
    for (int c = 0; c < 4; c++) {
        f32x4 bb4 = *(const f32x4*)(b1 + (4 * f + c) * 16 + quad * 4);
#pragma unroll
        for (int et = 0; et < 4; et++) {
            bf16x4 hv;
#pragma unroll
            for (int g = 0; g < 4; g++)
                hv[g] = (__bf16)fmaxf(acc[c][et][g] + bb4[g], 0.f);
            *(bf16x4*)(sHid + (q * 64 + et * 16 + r) * HS3
                       + (4 * f + c) * 16 + quad * 4) = hv;
        }
    }

    // ---- Phase B: msgT = (hid @ W2)^T, K=128 in 4 chunks ----
    f32x4 acc2[4][4];
#pragma unroll
    for (int c = 0; c < 4; c++)
#pragma unroll
        for (int et = 0; et < 4; et++) acc2[c][et] = (f32x4){0.f, 0.f, 0.f, 0.f};

#pragma unroll
    for (int kc = 0; kc < 4; kc++) {
        __syncthreads();                // also orders epilogue-A sHid writes
        *(f32x4*)(sW + tid * 8) = wnext;
        if (kc < 3)
            wnext = *(const f32x4*)(W + (9 + kc) * 4096 + tid * 8);
        __syncthreads();
        const int kk = kc * 32 + quad * 8;
        bf16x8 Bf[4];
#pragma unroll
        for (int et = 0; et < 4; et++)
            Bf[et] = *(const bf16x8*)(sHid + (q * 64 + et * 16 + r) * HS3 + kk);
        bf16x8 Af[4];
#pragma unroll
        for (int c = 0; c < 4; c++)
            Af[c] = *(const bf16x8*)(sW + (4 * f + c) * 512 + lane * 8);
#pragma unroll
        for (int c = 0; c < 4; c++)
#pragma unroll
            for (int et = 0; et < 4; et++)
                acc2[c][et] = __builtin_amdgcn_mfma_f32_16x16x32_bf16(
                    Af[c], Bf[et], acc2[c][et], 0, 0, 0);
    }

    // ---- Phase C: two feat-half passes (sMsg aliases sHid) ----
#pragma unroll
    for (int p = 0; p < 2; p++) {
        __syncthreads();          // sHid reads done / prev pass reduction done
        if (f == p) {
#pragma unroll
            for (int c = 0; c < 4; c++) {
                f32x4 bb4 = *(const f32x4*)(b2 + (4 * f + c) * 16 + quad * 4);
#pragma unroll
                for (int et = 0; et < 4; et++) {
                    f32x4 mv;
#pragma unroll
                    for (int g = 0; g < 4; g++)
                        mv[g] = acc2[c][et][g] + bb4[g];
                    *(f32x4*)(sMsg + (q * 64 + et * 16 + r) * MS3
                              + c * 16 + quad * 4) = mv;
                }
            }
        }
        __syncthreads();
        // segmented reduction: 8 strips x 32 edges, 64 cols of this pass
        int j = tid & 63, strip = tid >> 6;
        int jcol = p * 64 + j;
        int e0 = strip * 32;
        float run = 0.f; int curd = -1;
        for (int qq = 0; qq < 32; qq++) {
            int d = sDstV[e0 + qq];
            float v = sMsg[(e0 + qq) * MS3 + j];
            if (d != curd) {
                if (curd >= 0) atomicAdd(agg + (size_t)curd * H + jcol, run);
                run = 0.f; curd = d;
            }
            if (d >= 0) run += v;
        }
        if (curd >= 0) atomicAdd(agg + (size_t)curd * H + jcol, run);
    }
}

// ---------------- GRU cell: split-precision MFMA, double-buffered B --------
// Also zeroes agg (for the next layer) after reading it.
__global__ __launch_bounds__(512, 2) void k_gru(
    float* __restrict__ h, __bf16* __restrict__ hb,
    float* __restrict__ agg,
    const __bf16* __restrict__ Wg,
    const float* __restrict__ bih, const float* __restrict__ bhh,
    int n_nodes)
{
    const int nb = blockIdx.x * 32;
    const int tid = threadIdx.x;
    __shared__ __bf16 sIn[4][32][HS];   // agg_hi, agg_lo, h_hi, h_lo (34.8 KB)

#pragma unroll
    for (int v = 0; v < 2; v++) {
        int idx = tid + 512 * v;
        int e = idx >> 5, c4 = (idx & 31) * 4;
        int n = nb + e;
        float4 av = {0.f, 0.f, 0.f, 0.f}, hv = {0.f, 0.f, 0.f, 0.f};
        if (n < n_nodes) {
            av = *(const float4*)(agg + (size_t)n * H + c4);
            hv = *(const float4*)(h + (size_t)n * H + c4);
            float4 z = {0.f, 0.f, 0.f, 0.f};
            *(float4*)(agg + (size_t)n * H + c4) = z;   // ready for next layer
        }
        bf16x4 ahi, alo, hhi, hlo;
        float af[4] = {av.x, av.y, av.z, av.w};
        float hf[4] = {hv.x, hv.y, hv.z, hv.w};
#pragma unroll
        for (int c = 0; c < 4; c++) {
            __bf16 ah = (__bf16)af[c]; ahi[c] = ah; alo[c] = (__bf16)(af[c] - (float)ah);
            __bf16 hh = (__bf16)hf[c]; hhi[c] = hh; hlo[c] = (__bf16)(hf[c] - (float)hh);
        }
        *(bf16x4*)&sIn[0][e][c4] = ahi;
        *(bf16x4*)&sIn[1][e][c4] = alo;
        *(bf16x4*)&sIn[2][e][c4] = hhi;
        *(bf16x4*)&sIn[3][e][c4] = hlo;
    }
    __syncthreads();

    const int lane = tid & 63, w = tid >> 6;     // w: 0..7
    const int r = lane & 15, quad = lane >> 4;
    const int jt = w;

    f32x4 acc[2][3][2];                  // [m][gate][mat]
#pragma unroll
    for (int m = 0; m < 2; m++)
#pragma unroll
        for (int g = 0; g < 3; g++)
#pragma unroll
            for (int mat = 0; mat < 2; mat++)
                acc[m][g][mat] = (f32x4){0.f, 0.f, 0.f, 0.f};

    bf16x8 B[2][12];
#pragma unroll
    for (int mat = 0; mat < 2; mat++)
#pragma unroll
    for (int g = 0; g < 3; g++)
#pragma unroll
    for (int sp = 0; sp < 2; sp++)
        B[0][mat * 6 + g * 2 + sp] = *(const bf16x8*)(Wg +
            ((((size_t)(mat * 2 + sp) * 4 + 0) * 24 + (g * 8 + jt)) * 64 + lane) * 8);

#pragma unroll
    for (int kc = 0; kc < 4; kc++) {
        const int cur = kc & 1, nxt = cur ^ 1;
        if (kc < 3) {
#pragma unroll
            for (int mat = 0; mat < 2; mat++)
#pragma unroll
            for (int g = 0; g < 3; g++)
#pragma unroll
            for (int sp = 0; sp < 2; sp++)
                B[nxt][mat * 6 + g * 2 + sp] = *(const bf16x8*)(Wg +
                    ((((size_t)(mat * 2 + sp) * 4 + (kc + 1)) * 24 + (g * 8 + jt)) * 64 + lane) * 8);
        }
        bf16x8 A[2][4];
#pragma unroll
        for (int m = 0; m < 2; m++)
#pragma unroll
            for (int s = 0; s < 4; s++)
                A[m][s] = *(const bf16x8*)&sIn[s][m * 16 + r][kc * 32 + quad * 8];
#pragma unroll
        for (int g = 0; g < 3; g++)
#pragma unroll
        for (int mat = 0; mat < 2; mat++) {
            bf16x8 bhi = B[cur][mat * 6 + g * 2 + 0];
            bf16x8 blo = B[cur][mat * 6 + g * 2 + 1];
            int s = mat * 2;
#pragma unroll
            for (int m = 0; m < 2; m++) {
                acc[m][g][mat] = __builtin_amdgcn_mfma_f32_16x16x32_bf16(
                    A[m][s], bhi, acc[m][g][mat], 0, 0, 0);
                acc[m][g][mat] = __builtin_amdgcn_mfma_f32_16x16x32_bf16(
                    A[m][s], blo, acc[m][g][mat], 0, 0, 0);
                acc[m][g][mat] = __builtin_amdgcn_mfma_f32_16x16x32_bf16(
                    A[m][s + 1], bhi, acc[m][g][mat], 0, 0, 0);
            }
        }
    }

    const int jcol = jt * 16 + r;
    float br_ = bih[jcol], bz_ = bih[128 + jcol], bn_ = bih[256 + jcol];
    float cr = bhh[jcol], cz = bhh[128 + jcol], cn = bhh[256 + jcol];
#pragma unroll
    for (int m = 0; m < 2; m++)
#pragma unroll
    for (int g4 = 0; g4 < 4; g4++) {
        int n = nb + m * 16 + quad * 4 + g4;
        if (n < n_nodes) {
            float ir = acc[m][0][0][g4], hr = acc[m][0][1][g4];
            float iz = acc[m][1][0][g4], hz = acc[m][1][1][g4];
            float in_ = acc[m][2][0][g4], hn = acc[m][2][1][g4];
            float hold = h[(size_t)n * H + jcol];
            float rr = 1.f / (1.f + expf(-(ir + br_ + hr + cr)));
            float zz = 1.f / (1.f + expf(-(iz + bz_ + hz + cz)));
            float nv = tanhf(in_ + bn_ + rr * (hn + cn));
            float out = (1.f - zz) * nv + zz * hold;
            h[(size_t)n * H + jcol] = out;
            hb[(size_t)n * H + jcol] = (__bf16)out;
        }
    }
}

// ---------------- readout: out = relu(h@Wr1+br1) @ Wr2 + br2 ---------------
__global__ __launch_bounds__(128) void k_readout(
    const float* __restrict__ h, const float* __restrict__ Wr1,
    const float* __restrict__ br1, const float* __restrict__ Wr2,
    const float* __restrict__ br2, float* __restrict__ out, int n_out)
{
    const int n0 = blockIdx.x * 16;
    const int tid = threadIdx.x;     // 128
    __shared__ float sh[16][H];      // 8 KB
    __shared__ float sRed[2][16];
    {
#pragma unroll
        for (int v = 0; v < 4; v++) {
            int idx = tid + 128 * v;          // float4 id, 512 total
            int e = idx >> 5, qq = (idx & 31) * 4;
            int n = n0 + e;
            if (n < n_out)
                *(float4*)&sh[e][qq] = *(const float4*)(h + (size_t)n * H + qq);
        }
    }
    __syncthreads();

    const int j = tid;
    float bb = br1[j];
    float acc[16];
#pragma unroll
    for (int e = 0; e < 16; e++) acc[e] = bb;
    for (int k = 0; k < H; k++) {
        float wv = Wr1[k * H + j];
#pragma unroll
        for (int e = 0; e < 16; e++) acc[e] += sh[e][k] * wv;
    }
    float w2 = Wr2[j];
    int lane = tid & 63, w = tid >> 6;
#pragma unroll
    for (int e = 0; e < 16; e++) {
        float val = fmaxf(acc[e], 0.f) * w2;
#pragma unroll
        for (int off = 32; off > 0; off >>= 1)
            val += __shfl_down(val, off, 64);
        if (lane == 0) sRed[w][e] = val;
    }
    __syncthreads();
    if (tid < 16 && n0 + tid < n_out)
        out[n0 + tid] = sRed[0][tid] + sRed[1][tid] + br2[0];
}

// ---------------------------------------------------------------------------
extern "C" void kernel_launch(void* const* d_in, const int* in_sizes, int n_in,
                              void* d_out, int out_size, void* d_ws, size_t ws_size,
                              hipStream_t stream)
{
    const float* x      = (const float*)d_in[0];
    const int*   eidx   = (const int*)d_in[1];
    const int*   etype  = (const int*)d_in[2];
    const float* Win    = (const float*)d_in[4];
    const float* bin    = (const float*)d_in[5];
    const float* W1     = (const float*)d_in[6];   // (3,2,256,128)
    const float* b1     = (const float*)d_in[7];   // (3,2,128)
    const float* W2     = (const float*)d_in[8];   // (3,2,128,128)
    const float* b2     = (const float*)d_in[9];   // (3,2,128)
    const float* Wih    = (const float*)d_in[10];  // (3,128,384)
    const float* bih    = (const float*)d_in[11];  // (3,384)
    const float* Whh    = (const float*)d_in[12];  // (3,128,384)
    const float* bhh    = (const float*)d_in[13];  // (3,384)
    const float* Wr1    = (const float*)d_in[14];
    const float* br1    = (const float*)d_in[15];
    const float* Wr2    = (const float*)d_in[16];
    const float* br2    = (const float*)d_in[17];

    const int n_nodes = in_sizes[0] / FEAT;
    const int n_edges = in_sizes[1] / 2;
    const int L = 3;
    const size_t nh = (size_t)n_nodes * H;

    const int* src = eidx;
    const int* dst = eidx + n_edges;

    // workspace carve-up
    float*  h    = (float*)d_ws;                    // 25.6 MB
    float*  agg  = h + nh;                          // 25.6 MB
    __bf16* hb   = (__bf16*)(agg + nh);             // 12.8 MB
    __bf16* Wsw  = hb + nh;                         // 6*12*4096 bf16
    __bf16* Wg   = Wsw + 6 * 12 * 4096;             // 3*WG_PER_LAYER bf16
    int* bucket  = (int*)(Wg + 3 * WG_PER_LAYER);   // n_edges
    int* cnt     = bucket + n_edges;                // 2*nn (also k_place cursors)
    int* offs    = cnt + 2 * n_nodes;               // 2*nn + 1
    int* bsum    = offs + 2 * n_nodes + 1;          // scan block sums

    const int nscan = 2 * n_nodes;
    const int nb = (nscan + 1023) / 1024;

    hipMemsetAsync(cnt, 0, (size_t)nscan * sizeof(int), stream);

    k_wconv<<<(6 * 12 * 4096 + 255) / 256, 256, 0, stream>>>(W1, W2, Wsw);
    k_wgconv<<<(3 * WG_PER_LAYER + 255) / 256, 256, 0, stream>>>(Wih, Whh, Wg);
    k_input<<<((int)nh + 255) / 256, 256, 0, stream>>>(x, Win, bin, h, hb, n_nodes);

    const int eb = (n_edges + 255) / 256;
    k_hist <<<eb, 256, 0, stream>>>(etype, dst, cnt, n_edges, n_nodes);
    k_scan1<<<nb, 1024, 0, stream>>>(cnt, bsum, nscan);
    k_scan2<<<1, 128, 0, stream>>>(bsum, offs, nb, nscan);
    k_scan3<<<nb, 1024, 0, stream>>>(cnt, bsum, offs, nscan);
    k_place<<<eb, 256, 0, stream>>>(etype, dst, offs, cnt, bucket, n_edges, n_nodes);

    // agg zeroed once here; k_gru re-zeroes it for the following layer
    hipMemsetAsync(agg, 0, nh * sizeof(float), stream);

    const dim3 mgrid((n_edges + TE3 - 1) / TE3 + 7, 2);
    for (int l = 0; l < L; l++) {
        k_msg<<<mgrid, 512, 0, stream>>>(
            hb, bucket, offs, src, dst,
            Wsw + (size_t)l * 2 * 12 * 4096,
            b1 + (size_t)l * 2 * H, b2 + (size_t)l * 2 * H,
            agg, n_edges, n_nodes);
        k_gru<<<(n_nodes + 31) / 32, 512, 0, stream>>>(
            h, hb, agg,
            Wg + (size_t)l * WG_PER_LAYER,
            bih + (size_t)l * 384, bhh + (size_t)l * 384,
            n_nodes);
    }

    k_readout<<<(out_size + 15) / 16, 128, 0, stream>>>(
        h, Wr1, br1, Wr2, br2, (float*)d_out, out_size);
}

// Round 11
// 624.083 us; speedup vs baseline: 1.1048x; 1.1048x over previous
//
#include <hip/hip_runtime.h>
#include <math.h>

// ---------------------------------------------------------------------------
// TannerGNN. Round 11: revert R10's regressions (XCD swizzle, in-loop global
// gathers, TE=256). R9 k_msg structure + feat-half/edge-quarter wave tiling
// (f=w&1, q=w>>1): halves LDS weight-broadcast traffic; wreg[8]+refill keeps
// VGPR<=128 for 2 blocks/CU. Bit-identical K-order and reduction strips =>
// absmax must stay exactly 0.02734375. Everything else unchanged from R9.
// N_NODES=50000, N_EDGES=400000, H=128, L=3, T=2, FEAT=4, N_DATA=40000.
// ---------------------------------------------------------------------------

#define H 128
#define TE2 128        // edges per message block
#define MS2 132        // sMsg row stride in f32
#define HS  136        // sHid/sIn row stride in bf16
#define FEAT 4
#define WG_PER_LAYER 196608   // 2 mat * 2 split * 4 kc * 24 jtg * 64 lane * 8

typedef __bf16 bf16x8 __attribute__((ext_vector_type(8)));
typedef __bf16 bf16x4 __attribute__((ext_vector_type(4)));
typedef float  f32x4  __attribute__((ext_vector_type(4)));

// ---------------- input projection: h = relu(x @ W_in + b_in) --------------
__global__ __launch_bounds__(256) void k_input(
    const float* __restrict__ x, const float* __restrict__ Win,
    const float* __restrict__ bin, float* __restrict__ h,
    __bf16* __restrict__ hb, int n_nodes)
{
    int idx = blockIdx.x * 256 + threadIdx.x;
    if (idx >= n_nodes * H) return;
    int n = idx >> 7, j = idx & 127;
    float acc = bin[j];
#pragma unroll
    for (int f = 0; f < FEAT; f++)
        acc += x[n * FEAT + f] * Win[f * H + j];
    float v = fmaxf(acc, 0.f);
    h[idx] = v;
    hb[idx] = (__bf16)v;
}

// ---------------- message-weight conversion: bf16, MFMA-fragment order -----
__global__ __launch_bounds__(256) void k_wconv(
    const float* __restrict__ W1, const float* __restrict__ W2,
    __bf16* __restrict__ Wsw)
{
    int gid = blockIdx.x * 256 + threadIdx.x;
    const int per_lt = 12 * 4096;
    if (gid >= 6 * per_lt) return;
    int lt = gid / per_lt, rem = gid % per_lt;
    int chunk = rem >> 12;
    int within = rem & 4095;
    int ct = within >> 9;
    int lane = (within >> 3) & 63;
    int j = within & 7;
    int r = lane & 15, quad = lane >> 4;
    int n = ct * 16 + r;
    float v;
    if (chunk < 8) {
        int k = chunk * 32 + quad * 8 + j;
        v = W1[((size_t)lt * 256 + k) * 128 + n];
    } else {
        int k = (chunk - 8) * 32 + quad * 8 + j;
        v = W2[((size_t)lt * 128 + k) * 128 + n];
    }
    Wsw[gid] = (__bf16)v;
}

// ---------------- GRU-weight conversion: hi/lo split, B-fragment order -----
__global__ __launch_bounds__(256) void k_wgconv(
    const float* __restrict__ Wih, const float* __restrict__ Whh,
    __bf16* __restrict__ Wg)
{
    int gid = blockIdx.x * 256 + threadIdx.x;
    if (gid >= 3 * WG_PER_LAYER) return;
    int layer = gid / WG_PER_LAYER, rem = gid % WG_PER_LAYER;
    int t = rem & 7;
    int lane = (rem >> 3) & 63;
    int jtg = (rem >> 9) % 24;
    int mk = rem / 12288;          // (mat*2+split)*4 + kc, 0..15
    int kc = mk & 3;
    int msplit = mk >> 2;          // 0..3
    int mat = msplit >> 1, split = msplit & 1;
    int r = lane & 15, quad = lane >> 4;
    int k = kc * 32 + quad * 8 + t;
    int n = jtg * 16 + r;
    const float* W = (mat ? Whh : Wih) + (size_t)layer * 128 * 384;
    float v = W[(size_t)k * 384 + n];
    __bf16 hi = (__bf16)v;
    Wg[gid] = split ? (__bf16)(v - (float)hi) : hi;
}

// ---------------- counting sort by key = type*nn + dst ---------------------
__global__ __launch_bounds__(256) void k_hist(
    const int* __restrict__ et, const int* __restrict__ dst,
    int* __restrict__ cnt, int n_edges, int nn)
{
    int i = blockIdx.x * 256 + threadIdx.x;
    if (i < n_edges) atomicAdd(&cnt[et[i] * nn + dst[i]], 1);
}

__global__ __launch_bounds__(1024) void k_scan1(
    const int* __restrict__ cnt, int* __restrict__ bsum, int n)
{
    int i = blockIdx.x * 1024 + threadIdx.x;
    int v = (i < n) ? cnt[i] : 0;
#pragma unroll
    for (int off = 32; off > 0; off >>= 1) v += __shfl_down(v, off, 64);
    __shared__ int ws[16];
    int lane = threadIdx.x & 63, w = threadIdx.x >> 6;
    if (lane == 0) ws[w] = v;
    __syncthreads();
    if (threadIdx.x < 16) {
        int x = ws[threadIdx.x];
#pragma unroll
        for (int off = 8; off > 0; off >>= 1) x += __shfl_down(x, off, 64);
        if (threadIdx.x == 0) bsum[blockIdx.x] = x;
    }
}

__global__ __launch_bounds__(128) void k_scan2(
    int* __restrict__ bsum, int* __restrict__ offs, int nb, int n)
{
    int lane = threadIdx.x & 63, w = threadIdx.x >> 6;
    int v = (threadIdx.x < nb) ? bsum[threadIdx.x] : 0;
    int orig = v;
#pragma unroll
    for (int off = 1; off < 64; off <<= 1) {
        int t = __shfl_up(v, off, 64);
        if (lane >= off) v += t;
    }
    __shared__ int w0sum;
    if (threadIdx.x == 63) w0sum = v;
    __syncthreads();
    int ex = v - orig + (w ? w0sum : 0);
    if (threadIdx.x < nb) bsum[threadIdx.x] = ex;
    if (threadIdx.x == nb - 1) offs[n] = ex + orig;
}

__global__ __launch_bounds__(1024) void k_scan3(
    const int* __restrict__ cnt, const int* __restrict__ bsum,
    int* __restrict__ offs, int n)
{
    int i = blockIdx.x * 1024 + threadIdx.x;
    int v = (i < n) ? cnt[i] : 0;
    int orig = v;
    int lane = threadIdx.x & 63, w = threadIdx.x >> 6;
#pragma unroll
    for (int off = 1; off < 64; off <<= 1) {
        int t = __shfl_up(v, off, 64);
        if (lane >= off) v += t;
    }
    __shared__ int ws[16];
    if (lane == 63) ws[w] = v;
    __syncthreads();
    if (threadIdx.x < 16) {
        int x = ws[threadIdx.x];
#pragma unroll
        for (int off = 1; off < 16; off <<= 1) {
            int t = __shfl_up(x, off, 64);
            if (lane >= off) x += t;
        }
        ws[threadIdx.x] = x;
    }
    __syncthreads();
    int wbase = w ? ws[w - 1] : 0;
    if (i < n) offs[i] = bsum[blockIdx.x] + wbase + v - orig;
}

__global__ __launch_bounds__(256) void k_place(
    const int* __restrict__ et, const int* __restrict__ dst,
    const int* __restrict__ offs, int* __restrict__ cnt,
    int* __restrict__ bucket, int n_edges, int nn)
{
    int i = blockIdx.x * 256 + threadIdx.x;
    if (i < n_edges) {
        int key = et[i] * nn + dst[i];
        int p = atomicAdd(&cnt[key], -1) - 1;
        bucket[offs[key] + p] = i;
    }
}

// ---------------- fused MFMA message kernel --------------------------------
// Block = 128 dst-sorted edges of one type, 8 waves. Wave w: feat half
// f=w&1 (ct tiles 4f..4f+3), edge quarter q=w>>1 (subtiles u=0,1 of 16).
// Each wave reads 4 (not 8) weight fragments per chunk: halves the LDS
// weight broadcast. Transposed MFMA (A=weight frag, B=edge frag) as R9;
// per-acc K-order bit-identical to R9.
__global__ __launch_bounds__(512, 4) void k_msg(
    const __bf16* __restrict__ hb,
    const int* __restrict__ bucket, const int* __restrict__ offs,
    const int* __restrict__ src, const int* __restrict__ dst,
    const __bf16* __restrict__ Wsw, const float* __restrict__ b1l,
    const float* __restrict__ b2l,
    float* __restrict__ agg, int n_edges, int nn)
{
    const int t = blockIdx.y;
    const int c0 = offs[nn];
    const int cnt = t ? (n_edges - c0) : c0;
    const int base = t ? c0 : 0;
    const int start = blockIdx.x * TE2;
    if (start >= cnt) return;

    const __bf16* __restrict__ W = Wsw + (size_t)t * 12 * 4096;
    const float*  __restrict__ b1 = b1l + t * H;
    const float*  __restrict__ b2 = b2l + t * H;

    __shared__ __bf16 sW[4096];            // 8 KB weight chunk
    __shared__ float  sMsg[TE2 * MS2];     // 67584 B; sHid aliases
    __shared__ int    sDstV[TE2];
    __bf16* sHid = (__bf16*)sMsg;          // 128 rows x HS bf16 (34816 B)

    const int tid  = threadIdx.x;
    const int lane = tid & 63;
    const int w    = tid >> 6;
    const int r    = lane & 15;
    const int quad = lane >> 4;
    const int f    = w & 1;                // feat half
    const int q    = w >> 1;               // edge quarter

    // weight staging: Phase-A chunks 0..7; slot kc refilled with Phase-B
    // chunk kc right after staging (keeps VGPR budget at wreg[8]).
    f32x4 wreg[8];
#pragma unroll
    for (int c = 0; c < 8; c++)
        wreg[c] = *(const f32x4*)(W + c * 4096 + tid * 8);

    if (tid < TE2) {
        int i = start + tid;
        sDstV[tid] = (i < cnt) ? dst[bucket[base + i]] : -1;
    }

    int ei0 = start + q * 32 + r;
    int ei1 = ei0 + 16;
    int e0 = bucket[base + (ei0 < cnt ? ei0 : cnt - 1)];
    int e1 = bucket[base + (ei1 < cnt ? ei1 : cnt - 1)];
    const __bf16* ap0 = hb + (size_t)src[e0] * H;
    const __bf16* ap1 = hb + (size_t)src[e1] * H;
    const __bf16* dp0 = hb + (size_t)dst[e0] * H;
    const __bf16* dp1 = hb + (size_t)dst[e1] * H;

    bf16x8 afS[2][4];
#pragma unroll
    for (int i = 0; i < 4; i++) {
        afS[0][i] = *(const bf16x8*)(ap0 + i * 32 + quad * 8);
        afS[1][i] = *(const bf16x8*)(ap1 + i * 32 + quad * 8);
    }

    __syncthreads();

    // ---- Phase A: hidT = (cat @ W1)^T, K=256 in 8 chunks ----
    f32x4 acc[4][2];
#pragma unroll
    for (int c = 0; c < 4; c++)
#pragma unroll
        for (int u = 0; u < 2; u++) acc[c][u] = (f32x4){0.f, 0.f, 0.f, 0.f};

    bf16x8 afD[2][4];
#pragma unroll
    for (int kc = 0; kc < 8; kc++) {
        __syncthreads();                    // prev chunk fully consumed
        *(f32x4*)(sW + tid * 8) = wreg[kc];
        if (kc < 4)                         // refill slot with Phase-B chunk
            wreg[kc] = *(const f32x4*)(W + (8 + kc) * 4096 + tid * 8);
        __syncthreads();
        if (kc == 2) {                      // prefetch dst-half A frags
#pragma unroll
            for (int i = 0; i < 4; i++) {
                afD[0][i] = *(const bf16x8*)(dp0 + i * 32 + quad * 8);
                afD[1][i] = *(const bf16x8*)(dp1 + i * 32 + quad * 8);
            }
        }
        bf16x8 Bu0 = (kc < 4) ? afS[0][kc] : afD[0][kc - 4];
        bf16x8 Bu1 = (kc < 4) ? afS[1][kc] : afD[1][kc - 4];
        bf16x8 Af[4];
#pragma unroll
        for (int c = 0; c < 4; c++)
            Af[c] = *(const bf16x8*)(sW + (4 * f + c) * 512 + lane * 8);
#pragma unroll
        for (int c = 0; c < 4; c++) {
            acc[c][0] = __builtin_amdgcn_mfma_f32_16x16x32_bf16(
                Af[c], Bu0, acc[c][0], 0, 0, 0);
            acc[c][1] = __builtin_amdgcn_mfma_f32_16x16x32_bf16(
                Af[c], Bu1, acc[c][1], 0, 0, 0);
        }
    }

    // epilogue A: bias + relu -> bf16 -> sHid[edge][feat]
#pragma unroll
    for (int c = 0; c < 4; c++) {
        f32x4 bb4 = *(const f32x4*)(b1 + (4 * f + c) * 16 + quad * 4);
#pragma unroll
        for (int u = 0; u < 2; u++) {
            bf16x4 hv;
#pragma unroll
            for (int g = 0; g < 4; g++)
                hv[g] = (__bf16)fmaxf(acc[c][u][g] + bb4[g], 0.f);
            *(bf16x4*)(sHid + (q * 32 + u * 16 + r) * HS
                       + (4 * f + c) * 16 + quad * 4) = hv;
        }
    }

    // ---- Phase B: msgT = (hid @ W2)^T, K=128 in 4 chunks ----
    f32x4 acc2[4][2];
#pragma unroll
    for (int c = 0; c < 4; c++)
#pragma unroll
        for (int u = 0; u < 2; u++) acc2[c][u] = (f32x4){0.f, 0.f, 0.f, 0.f};

#pragma unroll
    for (int kc = 0; kc < 4; kc++) {
        __syncthreads();            // orders epilogue-A writes / prev reads
        *(f32x4*)(sW + tid * 8) = wreg[kc];
        __syncthreads();
        bf16x8 Bu[2];
#pragma unroll
        for (int u = 0; u < 2; u++)
            Bu[u] = *(const bf16x8*)(sHid + (q * 32 + u * 16 + r) * HS
                                     + kc * 32 + quad * 8);
        bf16x8 Af[4];
#pragma unroll
        for (int c = 0; c < 4; c++)
            Af[c] = *(const bf16x8*)(sW + (4 * f + c) * 512 + lane * 8);
#pragma unroll
        for (int c = 0; c < 4; c++) {
            acc2[c][0] = __builtin_amdgcn_mfma_f32_16x16x32_bf16(
                Af[c], Bu[0], acc2[c][0], 0, 0, 0);
            acc2[c][1] = __builtin_amdgcn_mfma_f32_16x16x32_bf16(
                Af[c], Bu[1], acc2[c][1], 0, 0, 0);
        }
    }

    __syncthreads();   // all sHid reads done before sMsg overwrites

    // ---- Phase C: msgs (+bias) -> sMsg[edge][feat], vectorized ----
#pragma unroll
    for (int c = 0; c < 4; c++) {
        f32x4 bb4 = *(const f32x4*)(b2 + (4 * f + c) * 16 + quad * 4);
#pragma unroll
        for (int u = 0; u < 2; u++) {
            f32x4 mv;
#pragma unroll
            for (int g = 0; g < 4; g++)
                mv[g] = acc2[c][u][g] + bb4[g];
            *(f32x4*)(sMsg + (q * 32 + u * 16 + r) * MS2
                      + (4 * f + c) * 16 + quad * 4) = mv;
        }
    }
    __syncthreads();

    // segmented reduction over dst-sorted rows; one atomic per run per col
    {
        int j = tid & 127, strip = tid >> 7;
        int e0s = strip * 32;
        float run = 0.f; int curd = -1;
        for (int qq = 0; qq < 32; qq++) {
            int d = sDstV[e0s + qq];
            float v = sMsg[(e0s + qq) * MS2 + j];
            if (d != curd) {
                if (curd >= 0) atomicAdd(agg + (size_t)curd * H + j, run);
                run = 0.f; curd = d;
            }
            if (d >= 0) run += v;
        }
        if (curd >= 0) atomicAdd(agg + (size_t)curd * H + j, run);
    }
}

// ---------------- GRU cell: split-precision MFMA, double-buffered B --------
// Also zeroes agg (for the next layer) after reading it.
__global__ __launch_bounds__(512, 2) void k_gru(
    float* __restrict__ h, __bf16* __restrict__ hb,
    float* __restrict__ agg,
    const __bf16* __restrict__ Wg,
    const float* __restrict__ bih, const float* __restrict__ bhh,
    int n_nodes)
{
    const int nb = blockIdx.x * 32;
    const int tid = threadIdx.x;
    __shared__ __bf16 sIn[4][32][HS];   // agg_hi, agg_lo, h_hi, h_lo (34.8 KB)

#pragma unroll
    for (int v = 0; v < 2; v++) {
        int idx = tid + 512 * v;
        int e = idx >> 5, c4 = (idx & 31) * 4;
        int n = nb + e;
        float4 av = {0.f, 0.f, 0.f, 0.f}, hv = {0.f, 0.f, 0.f, 0.f};
        if (n < n_nodes) {
            av = *(const float4*)(agg + (size_t)n * H + c4);
            hv = *(const float4*)(h + (size_t)n * H + c4);
            float4 z = {0.f, 0.f, 0.f, 0.f};
            *(float4*)(agg + (size_t)n * H + c4) = z;   // ready for next layer
        }
        bf16x4 ahi, alo, hhi, hlo;
        float af[4] = {av.x, av.y, av.z, av.w};
        float hf[4] = {hv.x, hv.y, hv.z, hv.w};
#pragma unroll
        for (int c = 0; c < 4; c++) {
            __bf16 ah = (__bf16)af[c]; ahi[c] = ah; alo[c] = (__bf16)(af[c] - (float)ah);
            __bf16 hh = (__bf16)hf[c]; hhi[c] = hh; hlo[c] = (__bf16)(hf[c] - (float)hh);
        }
        *(bf16x4*)&sIn[0][e][c4] = ahi;
        *(bf16x4*)&sIn[1][e][c4] = alo;
        *(bf16x4*)&sIn[2][e][c4] = hhi;
        *(bf16x4*)&sIn[3][e][c4] = hlo;
    }
    __syncthreads();

    const int lane = tid & 63, w = tid >> 6;     // w: 0..7
    const int r = lane & 15, quad = lane >> 4;
    const int jt = w;

    f32x4 acc[2][3][2];                  // [m][gate][mat]
#pragma unroll
    for (int m = 0; m < 2; m++)
#pragma unroll
        for (int g = 0; g < 3; g++)
#pragma unroll
            for (int mat = 0; mat < 2; mat++)
                acc[m][g][mat] = (f32x4){0.f, 0.f, 0.f, 0.f};

    bf16x8 B[2][12];
#pragma unroll
    for (int mat = 0; mat < 2; mat++)
#pragma unroll
    for (int g = 0; g < 3; g++)
#pragma unroll
    for (int sp = 0; sp < 2; sp++)
        B[0][mat * 6 + g * 2 + sp] = *(const bf16x8*)(Wg +
            ((((size_t)(mat * 2 + sp) * 4 + 0) * 24 + (g * 8 + jt)) * 64 + lane) * 8);

#pragma unroll
    for (int kc = 0; kc < 4; kc++) {
        const int cur = kc & 1, nxt = cur ^ 1;
        if (kc < 3) {
#pragma unroll
            for (int mat = 0; mat < 2; mat++)
#pragma unroll
            for (int g = 0; g < 3; g++)
#pragma unroll
            for (int sp = 0; sp < 2; sp++)
                B[nxt][mat * 6 + g * 2 + sp] = *(const bf16x8*)(Wg +
                    ((((size_t)(mat * 2 + sp) * 4 + (kc + 1)) * 24 + (g * 8 + jt)) * 64 + lane) * 8);
        }
        bf16x8 A[2][4];
#pragma unroll
        for (int m = 0; m < 2; m++)
#pragma unroll
            for (int s = 0; s < 4; s++)
                A[m][s] = *(const bf16x8*)&sIn[s][m * 16 + r][kc * 32 + quad * 8];
#pragma unroll
        for (int g = 0; g < 3; g++)
#pragma unroll
        for (int mat = 0; mat < 2; mat++) {
            bf16x8 bhi = B[cur][mat * 6 + g * 2 + 0];
            bf16x8 blo = B[cur][mat * 6 + g * 2 + 1];
            int s = mat * 2;
#pragma unroll
            for (int m = 0; m < 2; m++) {
                acc[m][g][mat] = __builtin_amdgcn_mfma_f32_16x16x32_bf16(
                    A[m][s], bhi, acc[m][g][mat], 0, 0, 0);
                acc[m][g][mat] = __builtin_amdgcn_mfma_f32_16x16x32_bf16(
                    A[m][s], blo, acc[m][g][mat], 0, 0, 0);
                acc[m][g][mat] = __builtin_amdgcn_mfma_f32_16x16x32_bf16(
                    A[m][s + 1], bhi, acc[m][g][mat], 0, 0, 0);
            }
        }
    }

    const int jcol = jt * 16 + r;
    float br_ = bih[jcol], bz_ = bih[128 + jcol], bn_ = bih[256 + jcol];
    float cr = bhh[jcol], cz = bhh[128 + jcol], cn = bhh[256 + jcol];
#pragma unroll
    for (int m = 0; m < 2; m++)
#pragma unroll
    for (int g4 = 0; g4 < 4; g4++) {
        int n = nb + m * 16 + quad * 4 + g4;
        if (n < n_nodes) {
            float ir = acc[m][0][0][g4], hr = acc[m][0][1][g4];
            float iz = acc[m][1][0][g4], hz = acc[m][1][1][g4];
            float in_ = acc[m][2][0][g4], hn = acc[m][2][1][g4];
            float hold = h[(size_t)n * H + jcol];
            float rr = 1.f / (1.f + expf(-(ir + br_ + hr + cr)));
            float zz = 1.f / (1.f + expf(-(iz + bz_ + hz + cz)));
            float nv = tanhf(in_ + bn_ + rr * (hn + cn));
            float out = (1.f - zz) * nv + zz * hold;
            h[(size_t)n * H + jcol] = out;
            hb[(size_t)n * H + jcol] = (__bf16)out;
        }
    }
}

// ---------------- readout: out = relu(h@Wr1+br1) @ Wr2 + br2 ---------------
__global__ __launch_bounds__(128) void k_readout(
    const float* __restrict__ h, const float* __restrict__ Wr1,
    const float* __restrict__ br1, const float* __restrict__ Wr2,
    const float* __restrict__ br2, float* __restrict__ out, int n_out)
{
    const int n0 = blockIdx.x * 16;
    const int tid = threadIdx.x;     // 128
    __shared__ float sh[16][H];      // 8 KB
    __shared__ float sRed[2][16];
    {
#pragma unroll
        for (int v = 0; v < 4; v++) {
            int idx = tid + 128 * v;          // float4 id, 512 total
            int e = idx >> 5, qq = (idx & 31) * 4;
            int n = n0 + e;
            if (n < n_out)
                *(float4*)&sh[e][qq] = *(const float4*)(h + (size_t)n * H + qq);
        }
    }
    __syncthreads();

    const int j = tid;
    float bb = br1[j];
    float acc[16];
#pragma unroll
    for (int e = 0; e < 16; e++) acc[e] = bb;
    for (int k = 0; k < H; k++) {
        float wv = Wr1[k * H + j];
#pragma unroll
        for (int e = 0; e < 16; e++) acc[e] += sh[e][k] * wv;
    }
    float w2 = Wr2[j];
    int lane = tid & 63, w = tid >> 6;
#pragma unroll
    for (int e = 0; e < 16; e++) {
        float val = fmaxf(acc[e], 0.f) * w2;
#pragma unroll
        for (int off = 32; off > 0; off >>= 1)
            val += __shfl_down(val, off, 64);
        if (lane == 0) sRed[w][e] = val;
    }
    __syncthreads();
    if (tid < 16 && n0 + tid < n_out)
        out[n0 + tid] = sRed[0][tid] + sRed[1][tid] + br2[0];
}

// ---------------------------------------------------------------------------
extern "C" void kernel_launch(void* const* d_in, const int* in_sizes, int n_in,
                              void* d_out, int out_size, void* d_ws, size_t ws_size,
                              hipStream_t stream)
{
    const float* x      = (const float*)d_in[0];
    const int*   eidx   = (const int*)d_in[1];
    const int*   etype  = (const int*)d_in[2];
    const float* Win    = (const float*)d_in[4];
    const float* bin    = (const float*)d_in[5];
    const float* W1     = (const float*)d_in[6];   // (3,2,256,128)
    const float* b1     = (const float*)d_in[7];   // (3,2,128)
    const float* W2     = (const float*)d_in[8];   // (3,2,128,128)
    const float* b2     = (const float*)d_in[9];   // (3,2,128)
    const float* Wih    = (const float*)d_in[10];  // (3,128,384)
    const float* bih    = (const float*)d_in[11];  // (3,384)
    const float* Whh    = (const float*)d_in[12];  // (3,128,384)
    const float* bhh    = (const float*)d_in[13];  // (3,384)
    const float* Wr1    = (const float*)d_in[14];
    const float* br1    = (const float*)d_in[15];
    const float* Wr2    = (const float*)d_in[16];
    const float* br2    = (const float*)d_in[17];

    const int n_nodes = in_sizes[0] / FEAT;
    const int n_edges = in_sizes[1] / 2;
    const int L = 3;
    const size_t nh = (size_t)n_nodes * H;

    const int* src = eidx;
    const int* dst = eidx + n_edges;

    // workspace carve-up
    float*  h    = (float*)d_ws;                    // 25.6 MB
    float*  agg  = h + nh;                          // 25.6 MB
    __bf16* hb   = (__bf16*)(agg + nh);             // 12.8 MB
    __bf16* Wsw  = hb + nh;                         // 6*12*4096 bf16
    __bf16* Wg   = Wsw + 6 * 12 * 4096;             // 3*WG_PER_LAYER bf16
    int* bucket  = (int*)(Wg + 3 * WG_PER_LAYER);   // n_edges
    int* cnt     = bucket + n_edges;                // 2*nn (also k_place cursors)
    int* offs    = cnt + 2 * n_nodes;               // 2*nn + 1
    int* bsum    = offs + 2 * n_nodes + 1;          // scan block sums

    const int nscan = 2 * n_nodes;
    const int nb = (nscan + 1023) / 1024;

    hipMemsetAsync(cnt, 0, (size_t)nscan * sizeof(int), stream);

    k_wconv<<<(6 * 12 * 4096 + 255) / 256, 256, 0, stream>>>(W1, W2, Wsw);
    k_wgconv<<<(3 * WG_PER_LAYER + 255) / 256, 256, 0, stream>>>(Wih, Whh, Wg);
    k_input<<<((int)nh + 255) / 256, 256, 0, stream>>>(x, Win, bin, h, hb, n_nodes);

    const int eb = (n_edges + 255) / 256;
    k_hist <<<eb, 256, 0, stream>>>(etype, dst, cnt, n_edges, n_nodes);
    k_scan1<<<nb, 1024, 0, stream>>>(cnt, bsum, nscan);
    k_scan2<<<1, 128, 0, stream>>>(bsum, offs, nb, nscan);
    k_scan3<<<nb, 1024, 0, stream>>>(cnt, bsum, offs, nscan);
    k_place<<<eb, 256, 0, stream>>>(etype, dst, offs, cnt, bucket, n_edges, n_nodes);

    // agg zeroed once here; k_gru re-zeroes it for the following layer
    hipMemsetAsync(agg, 0, nh * sizeof(float), stream);

    const dim3 mgrid((n_edges + TE2 - 1) / TE2, 2);
    for (int l = 0; l < L; l++) {
        k_msg<<<mgrid, 512, 0, stream>>>(
            hb, bucket, offs, src, dst,
            Wsw + (size_t)l * 2 * 12 * 4096,
            b1 + (size_t)l * 2 * H, b2 + (size_t)l * 2 * H,
            agg, n_edges, n_nodes);
        k_gru<<<(n_nodes + 31) / 32, 512, 0, stream>>>(
            h, hb, agg,
            Wg + (size_t)l * WG_PER_LAYER,
            bih + (size_t)l * 384, bhh + (size_t)l * 384,
            n_nodes);
    }

    k_readout<<<(out_size + 15) / 16, 128, 0, stream>>>(
        h, Wr1, br1, Wr2, br2, (float*)d_out, out_size);
}